// Round 12
// baseline (323.159 us; speedup 1.0000x reference)
//
#include <hip/hip_runtime.h>
#include <cstdint>
#include <cstddef>

// GraphCluster: 3-layer GCN + assign head, 100K nodes / 1.6M edges.
// R12: GCN stack is LINEAR -> collapse all 4 graph ops into z <- Az + 1*c^T
// iterated 4x on a 16-dim state (Wt0 = W0W1W2Wa precomputed on device).
// R13: parallel weight chain. R14/R16: fused MLP. R15 FAILED (TLP loss).
// R17 FAILED (wide-gather agg). R18 FAILED BADLY (LDS-atomic agg).
// R19 WIN (2 nodes/wave merged CSR range, 366->333). R20 WIN (4 nodes/wave
// + prefix steering, 333->304). R21 NEUTRAL: "persistent-B" didn't
// materialize (VGPR=64 < 80 needed -> compiler reloads B per tile) and grid
// cap 768 kept occupancy at 26%.
// R22 (this round): (a) mlp grid cap 768->2560 (10 blocks/CU queued; LDS
// 8.7KB + 64 VGPR allow 8/CU) -- all three MLP variants sat at ~48us/600GB/s
// with nothing saturated = latency-bound, wave count never raised; (b) agg
// 8 adjacent nodes/wave (3rd step of the proven amortization lever), 8
// cumulative prefixes, per-node sums as differences, 2 nodes finalized/lane.

#define SCAN_CHUNK 2048

typedef _Float16 half8 __attribute__((ext_vector_type(8)));
typedef float floatx4 __attribute__((ext_vector_type(4)));

// ---------------------------------------------------------------- generic scan
__global__ __launch_bounds__(256) void scan_partial_k(const int* __restrict__ cnt, int N,
                                                      int* __restrict__ bsum) {
  __shared__ int red[256];
  int b = blockIdx.x, t = threadIdx.x;
  int base = b * SCAN_CHUNK + t * 8;
  int s = 0;
#pragma unroll
  for (int i = 0; i < 8; ++i) {
    int idx = base + i;
    if (idx < N) s += cnt[idx];
  }
  red[t] = s;
  __syncthreads();
  for (int off = 128; off > 0; off >>= 1) {
    if (t < off) red[t] += red[t + off];
    __syncthreads();
  }
  if (t == 0) bsum[b] = red[0];
}

__global__ __launch_bounds__(64) void scan_bsum_k(int* __restrict__ bsum, int NB) {
  int lane = threadIdx.x;
  int per = (NB + 63) >> 6;
  int beg = lane * per;
  int end = min(beg + per, NB);
  int s = 0;
  for (int i = beg; i < end; ++i) s += bsum[i];
  int ps = s;
  for (int off = 1; off < 64; off <<= 1) {
    int u = __shfl_up(ps, off, 64);
    if (lane >= off) ps += u;
  }
  int run = ps - s;
  for (int i = beg; i < end; ++i) {
    int c = bsum[i];
    bsum[i] = run;
    run += c;
  }
}

__global__ __launch_bounds__(256) void scan_apply_k(const int* __restrict__ cnt,
                                                    const int* __restrict__ bsum_excl, int N,
                                                    int* __restrict__ rowptr,
                                                    int* __restrict__ cursor, int E) {
  __shared__ int wave_sums[4];
  int b = blockIdx.x, t = threadIdx.x;
  int base = b * SCAN_CHUNK + t * 8;
  int v[8];
  int s = 0;
#pragma unroll
  for (int i = 0; i < 8; ++i) {
    int idx = base + i;
    v[i] = (idx < N) ? cnt[idx] : 0;
    s += v[i];
  }
  int lane = t & 63, wave = t >> 6;
  int ps = s;
  for (int off = 1; off < 64; off <<= 1) {
    int u = __shfl_up(ps, off, 64);
    if (lane >= off) ps += u;
  }
  if (lane == 63) wave_sums[wave] = ps;
  __syncthreads();
  int woff = 0;
  for (int w = 0; w < 4; ++w)
    if (w < wave) woff += wave_sums[w];
  int excl = woff + (ps - s) + bsum_excl[b];
#pragma unroll
  for (int i = 0; i < 8; ++i) {
    int idx = base + i;
    if (idx < N) {
      rowptr[idx] = excl;
      cursor[idx] = excl;
      excl += v[i];
    }
  }
  if (b == 0 && t == 0) rowptr[N] = E;
}

// ------------------------------------------------- scan-sorted CSR build
__global__ __launch_bounds__(256) void p1a_hist_k(const int* __restrict__ dst, int E, int G,
                                                  int B, int chunk, int* __restrict__ M) {
  __shared__ int h[256];
  int g = blockIdx.x, t = threadIdx.x;
  for (int i = t; i < B; i += 256) h[i] = 0;
  __syncthreads();
  int ebeg = g * chunk, eend = min(ebeg + chunk, E);
  for (int e = ebeg + t; e < eend; e += 256) atomicAdd(&h[dst[e] >> 9], 1);
  __syncthreads();
  for (int b = t; b < B; b += 256) M[(size_t)b * G + g] = h[b];
}

__global__ __launch_bounds__(256) void p1c_scatter_k(const int* __restrict__ src,
                                                     const int* __restrict__ dst, int E, int G,
                                                     int B, int chunk,
                                                     const int* __restrict__ scanned,
                                                     uint32_t* __restrict__ tmp) {
  __shared__ int off[256];
  int g = blockIdx.x, t = threadIdx.x;
  for (int b = t; b < B; b += 256) off[b] = scanned[(size_t)b * G + g];
  __syncthreads();
  int ebeg = g * chunk, eend = min(ebeg + chunk, E);
  for (int e = ebeg + t; e < eend; e += 256) {
    int d = dst[e];
    int b = d >> 9;
    int pos = atomicAdd(&off[b], 1);  // LDS cursor, private to this block
    tmp[pos] = ((uint32_t)(d & 511) << 17) | (uint32_t)src[e];
  }
}

__global__ __launch_bounds__(256) void p2_build_k(const uint32_t* __restrict__ tmp,
                                                  const int* __restrict__ scanned, int G, int N,
                                                  int E, int* __restrict__ rowptr,
                                                  int* __restrict__ col,
                                                  float* __restrict__ dinv,
                                                  float* __restrict__ dinv2) {
  __shared__ int hist[512];
  __shared__ int cur[512];
  __shared__ int wsum[4];
  int b = blockIdx.x, t = threadIdx.x;
  int node0 = b << 9;
  int nn = min(512, N - node0);
  int sbeg = scanned[(size_t)b * G];
  int send = scanned[(size_t)(b + 1) * G];
  for (int i = t; i < 512; i += 256) hist[i] = 0;
  __syncthreads();
  for (int e = sbeg + t; e < send; e += 256) atomicAdd(&hist[tmp[e] >> 17], 1);
  __syncthreads();
  int h0 = hist[2 * t], h1 = hist[2 * t + 1];
  int s = h0 + h1;
  int lane = t & 63, w = t >> 6;
  int ps = s;
  for (int o = 1; o < 64; o <<= 1) {
    int u = __shfl_up(ps, o, 64);
    if (lane >= o) ps += u;
  }
  if (lane == 63) wsum[w] = ps;
  __syncthreads();
  int woff = 0;
  for (int k = 0; k < 4; ++k)
    if (k < w) woff += wsum[k];
  int excl = sbeg + woff + (ps - s);
  if (2 * t < nn) {
    rowptr[node0 + 2 * t] = excl;
    cur[2 * t] = excl;
    dinv[node0 + 2 * t] = rsqrtf((float)(h0 + 1));
    dinv2[node0 + 2 * t] = 1.f / (float)(h0 + 1);
  }
  if (2 * t + 1 < nn) {
    rowptr[node0 + 2 * t + 1] = excl + h0;
    cur[2 * t + 1] = excl + h0;
    dinv[node0 + 2 * t + 1] = rsqrtf((float)(h1 + 1));
    dinv2[node0 + 2 * t + 1] = 1.f / (float)(h1 + 1);
  }
  if (b == 0 && t == 0) rowptr[N] = E;
  __syncthreads();
  for (int e = sbeg + t; e < send; e += 256) {
    uint32_t u = tmp[e];
    int pos = atomicAdd(&cur[u >> 17], 1);
    col[pos] = (int)(u & 0x1FFFF);
  }
}

// ------------------------------------------------- fallback CSR build (N large)
__global__ __launch_bounds__(256) void count_edges_k(const int* __restrict__ dst, int E,
                                                     int* __restrict__ cnt) {
  int idx = blockIdx.x * blockDim.x + threadIdx.x;
  int stride = gridDim.x * blockDim.x;
  for (int e = idx; e < E; e += stride) atomicAdd(&cnt[dst[e]], 1);
}

__global__ __launch_bounds__(256) void dinv_k(const int* __restrict__ cnt,
                                              float* __restrict__ dinv,
                                              float* __restrict__ dinv2, int N) {
  int i = blockIdx.x * blockDim.x + threadIdx.x;
  if (i < N) {
    dinv[i] = rsqrtf((float)(cnt[i] + 1));
    dinv2[i] = 1.f / (float)(cnt[i] + 1);
  }
}

__global__ __launch_bounds__(256) void fill_k(const int* __restrict__ src,
                                              const int* __restrict__ dst, int E,
                                              int* __restrict__ cursor, int* __restrict__ col) {
  int idx = blockIdx.x * blockDim.x + threadIdx.x;
  int stride = gridDim.x * blockDim.x;
  for (int e = idx; e < E; e += stride) {
    int d = dst[e];
    int pos = atomicAdd(&cursor[d], 1);
    col[pos] = src[e];
  }
}

// ---------------------------------------------------------------- weight prep
// Lane-ordered MFMA B-fragments for the two 128x128 MLP weights.
__global__ __launch_bounds__(256) void wprep_k(const float* __restrict__ fc1_W,
                                               const float* __restrict__ fc2_W,
                                               _Float16* __restrict__ Wb) {
  int idx = blockIdx.x * 256 + threadIdx.x;
  if (idx < 2 * 16384) {
    int mat = idx >> 14;
    int r = idx & 16383;
    int t = r >> 11;
    int ktb = (r >> 9) & 3;
    int lane = (r >> 3) & 63;
    int j = r & 7;
    int m = lane & 15, q = lane >> 4;
    int k = ktb * 32 + q * 8 + j;
    int n = t * 16 + m;
    const float* W = (mat == 0) ? fc1_W : fc2_W;
    Wb[idx] = (_Float16)W[(size_t)k * 128 + n];
  }
}

// ------------------------------------- parallel weight chain (R13)
__global__ __launch_bounds__(256) void chain_mm_k(const float* __restrict__ A,
                                                  const float* __restrict__ B,
                                                  float* __restrict__ C) {
  __shared__ float Bl[2048];
  int t = threadIdx.x;
  for (int i = t; i < 2048; i += 256) Bl[i] = B[i];
  __syncthreads();
  int idx = blockIdx.x * 256 + t;
  int row = idx >> 4, f = idx & 15;
  const float* Ar = A + (size_t)row * 128;
  float s = 0.f;
#pragma unroll 8
  for (int j = 0; j < 128; ++j) s = fmaf(Ar[j], Bl[j * 16 + f], s);
  C[idx] = s;
}

__global__ __launch_bounds__(256) void chain_frag_k(const float* __restrict__ W0,
                                                    const float* __restrict__ T1,
                                                    const float* __restrict__ T2,
                                                    const float* __restrict__ assign_W,
                                                    const float* __restrict__ gcn_b,
                                                    _Float16* __restrict__ WbT,
                                                    float* __restrict__ cvec) {
  int t = threadIdx.x;
  if (blockIdx.x < 8) {
    __shared__ float T1l[2048];
    for (int i = t; i < 2048; i += 256) T1l[i] = T1[i];
    __syncthreads();
    int idx = blockIdx.x * 256 + t;
    int ktb = idx >> 9;
    int lane = (idx >> 3) & 63;
    int jj = idx & 7;
    int m = lane & 15, qq = lane >> 4;
    int k = ktb * 32 + qq * 8 + jj;
    const float* Ar = W0 + (size_t)k * 128;
    float s = 0.f;
#pragma unroll 8
    for (int j = 0; j < 128; ++j) s = fmaf(Ar[j], T1l[j * 16 + m], s);
    WbT[idx] = (_Float16)s;
  } else {
    if (t < 16) {
      float s3 = 0.f, s2 = 0.f, s1 = 0.f;
      for (int k = 0; k < 128; ++k) {
        s3 += gcn_b[k] * T1[k * 16 + t];
        s2 += gcn_b[128 + k] * T2[k * 16 + t];
        s1 += gcn_b[256 + k] * assign_W[k * 16 + t];
      }
      cvec[t] = s3;
      cvec[16 + t] = s2;
      cvec[32 + t] = s1;
    }
  }
}

// ------------------------------------- fused MLP + projection (R21/R22)
// Wave w owns cols [w*32, w*32+32); B-frags loaded per block (L2-hot).
// Block grid-strides over 16-row tiles; 4 waves co-compute each tile via
// shared hA/hB (2 barriers/iter). R22: grid cap 2560 (was 768) -> 8+
// blocks/CU resident, ~2.7x outstanding X loads (latency-bound fix).
__global__ __launch_bounds__(256) void mlp_pers_k(const float* __restrict__ X,
                                                  const _Float16* __restrict__ Wb,
                                                  const float* __restrict__ fc1_b,
                                                  const float* __restrict__ fc2_b,
                                                  const _Float16* __restrict__ WbT,
                                                  const float* __restrict__ dinv,
                                                  _Float16* __restrict__ S, int N,
                                                  int ntiles) {
  __shared__ _Float16 hA[16 * 136];
  __shared__ _Float16 hB[16 * 136];
  const int tid = threadIdx.x;
  const int w = tid >> 6, lane = tid & 63;
  const int m = lane & 15, q = lane >> 4;
  const _Float16* Wb2 = Wb + 16384;

  half8 b1[2][4], b2[2][4], bt[4];
#pragma unroll
  for (int t = 0; t < 2; ++t)
#pragma unroll
    for (int ktb = 0; ktb < 4; ++ktb) {
      b1[t][ktb] = *(const half8*)(Wb + (((size_t)(2 * w + t) * 4 + ktb) * 64 + lane) * 8);
      b2[t][ktb] = *(const half8*)(Wb2 + (((size_t)(2 * w + t) * 4 + ktb) * 64 + lane) * 8);
    }
#pragma unroll
  for (int ktb = 0; ktb < 4; ++ktb)
    bt[ktb] = *(const half8*)(WbT + ((size_t)ktb * 64 + lane) * 8);
  float bz1[2], bz2[2];
#pragma unroll
  for (int t = 0; t < 2; ++t) {
    bz1[t] = fc1_b[(2 * w + t) * 16 + m];
    bz2[t] = fc2_b[(2 * w + t) * 16 + m];
  }

  for (int tile = blockIdx.x; tile < ntiles; tile += gridDim.x) {
    int r0 = tile * 16;
    int rowA = r0 + m;
    bool valid = rowA < N;
    half8 xa[4];
#pragma unroll
    for (int ktb = 0; ktb < 4; ++ktb) {
      half8 a = {0, 0, 0, 0, 0, 0, 0, 0};
      if (valid) {
        const float* Ap = X + (size_t)rowA * 128 + ktb * 32 + q * 8;
        float4 f0 = *(const float4*)Ap;
        float4 f1 = *(const float4*)(Ap + 4);
        a[0] = (_Float16)f0.x; a[1] = (_Float16)f0.y;
        a[2] = (_Float16)f0.z; a[3] = (_Float16)f0.w;
        a[4] = (_Float16)f1.x; a[5] = (_Float16)f1.y;
        a[6] = (_Float16)f1.z; a[7] = (_Float16)f1.w;
      }
      xa[ktb] = a;
    }
    // ---- fc1 (B in regs)
    floatx4 acc0 = (floatx4){0.f, 0.f, 0.f, 0.f};
    floatx4 acc1 = (floatx4){0.f, 0.f, 0.f, 0.f};
#pragma unroll
    for (int ktb = 0; ktb < 4; ++ktb) {
      acc0 = __builtin_amdgcn_mfma_f32_16x16x32_f16(xa[ktb], b1[0][ktb], acc0, 0, 0, 0);
      acc1 = __builtin_amdgcn_mfma_f32_16x16x32_f16(xa[ktb], b1[1][ktb], acc1, 0, 0, 0);
    }
#pragma unroll
    for (int t = 0; t < 2; ++t) {
      int colg = (2 * w + t) * 16 + m;
      float bz = bz1[t];
#pragma unroll
      for (int r = 0; r < 4; ++r) {
        float v = ((t == 0) ? acc0[r] : acc1[r]) + bz;
        v = 1.f / (1.f + __expf(-v));
        hA[(q * 4 + r) * 136 + colg] = (_Float16)v;
      }
    }
    __syncthreads();
    // ---- fc2 (A from hA, B in regs)
    acc0 = (floatx4){0.f, 0.f, 0.f, 0.f};
    acc1 = (floatx4){0.f, 0.f, 0.f, 0.f};
#pragma unroll
    for (int ktb = 0; ktb < 4; ++ktb) {
      half8 a = *(const half8*)(hA + m * 136 + ktb * 32 + q * 8);
      acc0 = __builtin_amdgcn_mfma_f32_16x16x32_f16(a, b2[0][ktb], acc0, 0, 0, 0);
      acc1 = __builtin_amdgcn_mfma_f32_16x16x32_f16(a, b2[1][ktb], acc1, 0, 0, 0);
    }
#pragma unroll
    for (int t = 0; t < 2; ++t) {
      int colg = (2 * w + t) * 16 + m;
      float bz = bz2[t];
#pragma unroll
      for (int r = 0; r < 4; ++r) {
        float v = ((t == 0) ? acc0[r] : acc1[r]) + bz;
        v = 1.f / (1.f + __expf(-v));
        hB[(q * 4 + r) * 136 + colg] = (_Float16)v;
      }
    }
    __syncthreads();
    // ---- proj (redundant in all waves; wave 0 stores)
    floatx4 p = (floatx4){0.f, 0.f, 0.f, 0.f};
#pragma unroll
    for (int ktb = 0; ktb < 4; ++ktb) {
      half8 a = *(const half8*)(hB + m * 136 + ktb * 32 + q * 8);
      p = __builtin_amdgcn_mfma_f32_16x16x32_f16(a, bt[ktb], p, 0, 0, 0);
    }
    if (w == 0) {
#pragma unroll
      for (int r = 0; r < 4; ++r) {
        int row = r0 + q * 4 + r;
        if (row < N) S[(size_t)row * 16 + m] = (_Float16)(p[r] * dinv[row]);
      }
    }
  }
}

// ---------------------------------------------------------------- aggregation
// R22: pull-mode, 8 ADJACENT nodes per wave over the merged contiguous CSR
// range [rowptr[n0], rowptr[n0+8]) (~128 edges). Slot j (lane>>4) takes 1/4,
// 8-wide gather unroll. 8 cumulative prefixes p0..p7 (p_k = sum over e<s_{k+1});
// per-node sums recovered as differences after the slot-reduce. Each lane
// finalizes nodes n0+2j and n0+2j+1 (all 64 lanes store).
template <bool FOUT32>
__global__ __launch_bounds__(256) void agg16o_k(const _Float16* __restrict__ xw,
                                                const int* __restrict__ rowptr,
                                                const int* __restrict__ col,
                                                const float* __restrict__ rowscale,
                                                const float* __restrict__ biasmul,
                                                const float* __restrict__ c,
                                                void* __restrict__ outv, int N) {
  int w = blockIdx.x * 4 + (threadIdx.x >> 6);
  int n0 = w * 8;
  if (n0 >= N) return;
  int lane = threadIdx.x & 63;
  int f = lane & 15;
  int j = lane >> 4;
  int b0 = rowptr[n0];
  int s1 = rowptr[min(n0 + 1, N)];
  int s2 = rowptr[min(n0 + 2, N)];
  int s3 = rowptr[min(n0 + 3, N)];
  int s4 = rowptr[min(n0 + 4, N)];
  int s5 = rowptr[min(n0 + 5, N)];
  int s6 = rowptr[min(n0 + 6, N)];
  int s7 = rowptr[min(n0 + 7, N)];
  int e8 = rowptr[min(n0 + 8, N)];
  int D = e8 - b0;
  int q = (D + 3) >> 2;
  int e = b0 + j * q;
  int ee = min(e + q, e8);
  float p0 = 0.f, p1 = 0.f, p2 = 0.f, p3 = 0.f, p4 = 0.f, p5 = 0.f, p6 = 0.f, p7 = 0.f;
  for (; e + 7 < ee; e += 8) {
    int cc[8];
#pragma unroll
    for (int i = 0; i < 8; ++i) cc[i] = col[e + i];
    float vv[8];
#pragma unroll
    for (int i = 0; i < 8; ++i) vv[i] = (float)xw[(size_t)cc[i] * 16 + f];
#pragma unroll
    for (int i = 0; i < 8; ++i) {
      int ei = e + i;
      float v = vv[i];
      p0 += (ei < s1) ? v : 0.f;
      p1 += (ei < s2) ? v : 0.f;
      p2 += (ei < s3) ? v : 0.f;
      p3 += (ei < s4) ? v : 0.f;
      p4 += (ei < s5) ? v : 0.f;
      p5 += (ei < s6) ? v : 0.f;
      p6 += (ei < s7) ? v : 0.f;
      p7 += v;
    }
  }
  for (; e < ee; ++e) {
    float v = (float)xw[(size_t)col[e] * 16 + f];
    p0 += (e < s1) ? v : 0.f;
    p1 += (e < s2) ? v : 0.f;
    p2 += (e < s3) ? v : 0.f;
    p3 += (e < s4) ? v : 0.f;
    p4 += (e < s5) ? v : 0.f;
    p5 += (e < s6) ? v : 0.f;
    p6 += (e < s7) ? v : 0.f;
    p7 += v;
  }
  p0 += __shfl_xor(p0, 16, 64); p0 += __shfl_xor(p0, 32, 64);
  p1 += __shfl_xor(p1, 16, 64); p1 += __shfl_xor(p1, 32, 64);
  p2 += __shfl_xor(p2, 16, 64); p2 += __shfl_xor(p2, 32, 64);
  p3 += __shfl_xor(p3, 16, 64); p3 += __shfl_xor(p3, 32, 64);
  p4 += __shfl_xor(p4, 16, 64); p4 += __shfl_xor(p4, 32, 64);
  p5 += __shfl_xor(p5, 16, 64); p5 += __shfl_xor(p5, 32, 64);
  p6 += __shfl_xor(p6, 16, 64); p6 += __shfl_xor(p6, 32, 64);
  p7 += __shfl_xor(p7, 16, 64); p7 += __shfl_xor(p7, 32, 64);
  // lane (j, f) finalizes nodes n0+2j (sum = a0-lo) and n0+2j+1 (a1-a0)
  float lo = (j == 0) ? 0.f : (j == 1) ? p1 : (j == 2) ? p3 : p5;
  float a0 = (j == 0) ? p0 : (j == 1) ? p2 : (j == 2) ? p4 : p6;
  float a1 = (j == 0) ? p1 : (j == 1) ? p3 : (j == 2) ? p5 : p7;
  int nA = n0 + 2 * j;
  int nB = nA + 1;
  if (nA < N) {
    float a = (a0 - lo) + (float)xw[(size_t)nA * 16 + f];
    float bm = biasmul ? biasmul[nA] : 1.f;
    float o = fmaf(a, rowscale[nA], bm * c[f]);
    if (FOUT32)
      ((float*)outv)[(size_t)nA * 16 + f] = o;
    else
      ((_Float16*)outv)[(size_t)nA * 16 + f] = (_Float16)o;
  }
  if (nB < N) {
    float a = (a1 - a0) + (float)xw[(size_t)nB * 16 + f];
    float bm = biasmul ? biasmul[nB] : 1.f;
    float o = fmaf(a, rowscale[nB], bm * c[f]);
    if (FOUT32)
      ((float*)outv)[(size_t)nB * 16 + f] = o;
    else
      ((_Float16*)outv)[(size_t)nB * 16 + f] = (_Float16)o;
  }
}

// ---------------------------------------------------------------- launch
extern "C" void kernel_launch(void* const* d_in, const int* in_sizes, int n_in,
                              void* d_out, int out_size, void* d_ws, size_t ws_size,
                              hipStream_t stream) {
  const int* adj = (const int*)d_in[0];
  const float* X = (const float*)d_in[1];
  const float* fc1_W = (const float*)d_in[2];
  const float* fc1_b = (const float*)d_in[3];
  const float* fc2_W = (const float*)d_in[4];
  const float* fc2_b = (const float*)d_in[5];
  const float* gcn_W = (const float*)d_in[6];
  const float* gcn_b = (const float*)d_in[7];
  const float* assign_W = (const float*)d_in[8];
  const float* assign_b = (const float*)d_in[9];
  const int E = in_sizes[0] / 2;
  const int N = in_sizes[1] / 128;
  const int* src = adj;
  const int* dst = adj + E;

  char* ws = (char*)d_ws;
  size_t off = 0;
  auto alloc = [&](size_t bytes) {
    void* p = ws + off;
    off = (off + bytes + 511) & ~(size_t)511;
    return p;
  };
  const int G = 256;
  const int B = (N + 511) >> 9;
  const int L = B * G;
  _Float16* SA = (_Float16*)alloc((size_t)N * 16 * 2);  // 3.2 MB state
  _Float16* SB = (_Float16*)alloc((size_t)N * 16 * 2);  // 3.2 MB state
  _Float16* Wb = (_Float16*)alloc((size_t)2 * 16384 * 2);
  _Float16* WbT = (_Float16*)alloc(2048 * 2);
  float* T2g = (float*)alloc(2048 * 4);
  float* T1g = (float*)alloc(2048 * 4);
  float* cvec = (float*)alloc(48 * 4);
  float* dinv = (float*)alloc((size_t)N * 4);
  float* dinv2 = (float*)alloc((size_t)N * 4);
  int* rowptr = (int*)alloc((size_t)(N + 1) * 4);
  int* col = (int*)alloc((size_t)E * 4);
  uint32_t* tmp = (uint32_t*)alloc((size_t)E * 4);
  int* M = (int*)alloc((size_t)L * 4);
  int* scanned = (int*)alloc((size_t)(L + 1) * 4);
  int* scanscratch = (int*)alloc((size_t)L * 4);
  int* bsum = (int*)alloc(4096);
  int* cnt = (int*)alloc((size_t)N * 4);     // fallback path only
  int* cursor = (int*)alloc((size_t)N * 4);  // fallback path only

  wprep_k<<<(2 * 16384 + 255) / 256, 256, 0, stream>>>(fc1_W, fc2_W, Wb);
  // parallel weight chain: T2 = W2@Wa, T1 = W1@T2, WbT = frag(W0@T1), cvec
  chain_mm_k<<<8, 256, 0, stream>>>(gcn_W + 32768, assign_W, T2g);
  chain_mm_k<<<8, 256, 0, stream>>>(gcn_W + 16384, T2g, T1g);
  chain_frag_k<<<9, 256, 0, stream>>>(gcn_W, T1g, T2g, assign_W, gcn_b, WbT, cvec);

  if (N <= (1 << 17)) {
    const int chunk = (E + G - 1) / G;
    const int NBL = (L + SCAN_CHUNK - 1) / SCAN_CHUNK;
    p1a_hist_k<<<G, 256, 0, stream>>>(dst, E, G, B, chunk, M);
    scan_partial_k<<<NBL, 256, 0, stream>>>(M, L, bsum);
    scan_bsum_k<<<1, 64, 0, stream>>>(bsum, NBL);
    scan_apply_k<<<NBL, 256, 0, stream>>>(M, bsum, L, scanned, scanscratch, E);
    p1c_scatter_k<<<G, 256, 0, stream>>>(src, dst, E, G, B, chunk, scanned, tmp);
    p2_build_k<<<B, 256, 0, stream>>>(tmp, scanned, G, N, E, rowptr, col, dinv, dinv2);
  } else {
    const int NB = (N + SCAN_CHUNK - 1) / SCAN_CHUNK;
    hipMemsetAsync(cnt, 0, (size_t)N * 4, stream);
    count_edges_k<<<2048, 256, 0, stream>>>(dst, E, cnt);
    dinv_k<<<(N + 255) / 256, 256, 0, stream>>>(cnt, dinv, dinv2, N);
    scan_partial_k<<<NB, 256, 0, stream>>>(cnt, N, bsum);
    scan_bsum_k<<<1, 64, 0, stream>>>(bsum, NB);
    scan_apply_k<<<NB, 256, 0, stream>>>(cnt, bsum, N, rowptr, cursor, E);
    fill_k<<<2048, 256, 0, stream>>>(src, dst, E, cursor, col);
  }

  int ntiles = (N + 15) / 16;
  int gm = ntiles < 2560 ? ntiles : 2560;  // R22: was 768 -> occupancy cap 100%
  int ab8 = (N + 31) / 32;                 // 8 nodes/wave, 4 waves/block
  // Fused MLP front-end + collapsed-weight projection (needs dinv from CSR).
  mlp_pers_k<<<gm, 256, 0, stream>>>(X, Wb, fc1_b, fc2_b, WbT, dinv, SA, N, ntiles);
  // Collapsed linear graph stack: S = D^{-1/2} z, z <- Az + 1 c^T, 4 times.
  agg16o_k<false><<<ab8, 256, 0, stream>>>(SA, rowptr, col, dinv2, dinv, cvec, SB, N);
  agg16o_k<false><<<ab8, 256, 0, stream>>>(SB, rowptr, col, dinv2, dinv, cvec + 16, SA, N);
  agg16o_k<false><<<ab8, 256, 0, stream>>>(SA, rowptr, col, dinv2, dinv, cvec + 32, SB, N);
  agg16o_k<true><<<ab8, 256, 0, stream>>>(SB, rowptr, col, dinv, nullptr, assign_b,
                                          (float*)d_out, N);
}

// Round 14
// 296.887 us; speedup vs baseline: 1.0885x; 1.0885x over previous
//
#include <hip/hip_runtime.h>
#include <cstdint>
#include <cstddef>

// GraphCluster: 3-layer GCN + assign head, 100K nodes / 1.6M edges.
// R12: GCN stack is LINEAR -> collapse all 4 graph ops into z <- Az + 1*c^T
// iterated 4x on a 16-dim state (Wt0 = W0W1W2Wa precomputed on device).
// R13: parallel weight chain. R14/R16: fused MLP (LDS-staged B-frags).
// R15 FAILED (TLP loss). R17 FAILED (wide-gather agg). R18 FAILED BADLY
// (LDS-atomic agg). R19 WIN (2 nodes/wave, 366->333). R20 WIN (4 nodes/wave
// + prefix steering, 333->304). R21 NEUTRAL (persistent-B didn't materialize).
// R22 FAILED both prongs (mlp occupancy neutral -> stop touching mlp;
// 8 nodes/wave slower -> amortization saturates at 4).
// R23 (resubmit; previous attempt hit an infra container failure, no bench):
// exact R20 config (proven 304us) + the ONE clean change never isolated:
// CSR-build G 256->1024 (p1a/p1c were 25-deep serial loops at 1 block/CU;
// 4x blocks = 4x outstanding loads). If CSR doesn't move, practical floor.

#define SCAN_CHUNK 2048

typedef _Float16 half8 __attribute__((ext_vector_type(8)));
typedef float floatx4 __attribute__((ext_vector_type(4)));

// ---------------------------------------------------------------- generic scan
__global__ __launch_bounds__(256) void scan_partial_k(const int* __restrict__ cnt, int N,
                                                      int* __restrict__ bsum) {
  __shared__ int red[256];
  int b = blockIdx.x, t = threadIdx.x;
  int base = b * SCAN_CHUNK + t * 8;
  int s = 0;
#pragma unroll
  for (int i = 0; i < 8; ++i) {
    int idx = base + i;
    if (idx < N) s += cnt[idx];
  }
  red[t] = s;
  __syncthreads();
  for (int off = 128; off > 0; off >>= 1) {
    if (t < off) red[t] += red[t + off];
    __syncthreads();
  }
  if (t == 0) bsum[b] = red[0];
}

__global__ __launch_bounds__(64) void scan_bsum_k(int* __restrict__ bsum, int NB) {
  int lane = threadIdx.x;
  int per = (NB + 63) >> 6;
  int beg = lane * per;
  int end = min(beg + per, NB);
  int s = 0;
  for (int i = beg; i < end; ++i) s += bsum[i];
  int ps = s;
  for (int off = 1; off < 64; off <<= 1) {
    int u = __shfl_up(ps, off, 64);
    if (lane >= off) ps += u;
  }
  int run = ps - s;
  for (int i = beg; i < end; ++i) {
    int c = bsum[i];
    bsum[i] = run;
    run += c;
  }
}

__global__ __launch_bounds__(256) void scan_apply_k(const int* __restrict__ cnt,
                                                    const int* __restrict__ bsum_excl, int N,
                                                    int* __restrict__ rowptr,
                                                    int* __restrict__ cursor, int E) {
  __shared__ int wave_sums[4];
  int b = blockIdx.x, t = threadIdx.x;
  int base = b * SCAN_CHUNK + t * 8;
  int v[8];
  int s = 0;
#pragma unroll
  for (int i = 0; i < 8; ++i) {
    int idx = base + i;
    v[i] = (idx < N) ? cnt[idx] : 0;
    s += v[i];
  }
  int lane = t & 63, wave = t >> 6;
  int ps = s;
  for (int off = 1; off < 64; off <<= 1) {
    int u = __shfl_up(ps, off, 64);
    if (lane >= off) ps += u;
  }
  if (lane == 63) wave_sums[wave] = ps;
  __syncthreads();
  int woff = 0;
  for (int w = 0; w < 4; ++w)
    if (w < wave) woff += wave_sums[w];
  int excl = woff + (ps - s) + bsum_excl[b];
#pragma unroll
  for (int i = 0; i < 8; ++i) {
    int idx = base + i;
    if (idx < N) {
      rowptr[idx] = excl;
      cursor[idx] = excl;
      excl += v[i];
    }
  }
  if (b == 0 && t == 0) rowptr[N] = E;
}

// ------------------------------------------------- scan-sorted CSR build
// R23: G=1024 launch (4 blocks/CU) for latency hiding; bins stay 512-node
// (B = ceil(N/512) <= 256 for N <= 2^17).
__global__ __launch_bounds__(256) void p1a_hist_k(const int* __restrict__ dst, int E, int G,
                                                  int B, int chunk, int* __restrict__ M) {
  __shared__ int h[256];
  int g = blockIdx.x, t = threadIdx.x;
  for (int i = t; i < B; i += 256) h[i] = 0;
  __syncthreads();
  int ebeg = g * chunk, eend = min(ebeg + chunk, E);
  for (int e = ebeg + t; e < eend; e += 256) atomicAdd(&h[dst[e] >> 9], 1);
  __syncthreads();
  for (int b = t; b < B; b += 256) M[(size_t)b * G + g] = h[b];
}

__global__ __launch_bounds__(256) void p1c_scatter_k(const int* __restrict__ src,
                                                     const int* __restrict__ dst, int E, int G,
                                                     int B, int chunk,
                                                     const int* __restrict__ scanned,
                                                     uint32_t* __restrict__ tmp) {
  __shared__ int off[256];
  int g = blockIdx.x, t = threadIdx.x;
  for (int b = t; b < B; b += 256) off[b] = scanned[(size_t)b * G + g];
  __syncthreads();
  int ebeg = g * chunk, eend = min(ebeg + chunk, E);
  for (int e = ebeg + t; e < eend; e += 256) {
    int d = dst[e];
    int b = d >> 9;
    int pos = atomicAdd(&off[b], 1);  // LDS cursor, private to this block
    tmp[pos] = ((uint32_t)(d & 511) << 17) | (uint32_t)src[e];
  }
}

__global__ __launch_bounds__(256) void p2_build_k(const uint32_t* __restrict__ tmp,
                                                  const int* __restrict__ scanned, int G, int N,
                                                  int E, int* __restrict__ rowptr,
                                                  int* __restrict__ col,
                                                  float* __restrict__ dinv,
                                                  float* __restrict__ dinv2) {
  __shared__ int hist[512];
  __shared__ int cur[512];
  __shared__ int wsum[4];
  int b = blockIdx.x, t = threadIdx.x;
  int node0 = b << 9;
  int nn = min(512, N - node0);
  int sbeg = scanned[(size_t)b * G];
  int send = scanned[(size_t)(b + 1) * G];
  for (int i = t; i < 512; i += 256) hist[i] = 0;
  __syncthreads();
  for (int e = sbeg + t; e < send; e += 256) atomicAdd(&hist[tmp[e] >> 17], 1);
  __syncthreads();
  int h0 = hist[2 * t], h1 = hist[2 * t + 1];
  int s = h0 + h1;
  int lane = t & 63, w = t >> 6;
  int ps = s;
  for (int o = 1; o < 64; o <<= 1) {
    int u = __shfl_up(ps, o, 64);
    if (lane >= o) ps += u;
  }
  if (lane == 63) wsum[w] = ps;
  __syncthreads();
  int woff = 0;
  for (int k = 0; k < 4; ++k)
    if (k < w) woff += wsum[k];
  int excl = sbeg + woff + (ps - s);
  if (2 * t < nn) {
    rowptr[node0 + 2 * t] = excl;
    cur[2 * t] = excl;
    dinv[node0 + 2 * t] = rsqrtf((float)(h0 + 1));
    dinv2[node0 + 2 * t] = 1.f / (float)(h0 + 1);
  }
  if (2 * t + 1 < nn) {
    rowptr[node0 + 2 * t + 1] = excl + h0;
    cur[2 * t + 1] = excl + h0;
    dinv[node0 + 2 * t + 1] = rsqrtf((float)(h1 + 1));
    dinv2[node0 + 2 * t + 1] = 1.f / (float)(h1 + 1);
  }
  if (b == 0 && t == 0) rowptr[N] = E;
  __syncthreads();
  for (int e = sbeg + t; e < send; e += 256) {
    uint32_t u = tmp[e];
    int pos = atomicAdd(&cur[u >> 17], 1);
    col[pos] = (int)(u & 0x1FFFF);
  }
}

// ------------------------------------------------- fallback CSR build (N large)
__global__ __launch_bounds__(256) void count_edges_k(const int* __restrict__ dst, int E,
                                                     int* __restrict__ cnt) {
  int idx = blockIdx.x * blockDim.x + threadIdx.x;
  int stride = gridDim.x * blockDim.x;
  for (int e = idx; e < E; e += stride) atomicAdd(&cnt[dst[e]], 1);
}

__global__ __launch_bounds__(256) void dinv_k(const int* __restrict__ cnt,
                                              float* __restrict__ dinv,
                                              float* __restrict__ dinv2, int N) {
  int i = blockIdx.x * blockDim.x + threadIdx.x;
  if (i < N) {
    dinv[i] = rsqrtf((float)(cnt[i] + 1));
    dinv2[i] = 1.f / (float)(cnt[i] + 1);
  }
}

__global__ __launch_bounds__(256) void fill_k(const int* __restrict__ src,
                                              const int* __restrict__ dst, int E,
                                              int* __restrict__ cursor, int* __restrict__ col) {
  int idx = blockIdx.x * blockDim.x + threadIdx.x;
  int stride = gridDim.x * blockDim.x;
  for (int e = idx; e < E; e += stride) {
    int d = dst[e];
    int pos = atomicAdd(&cursor[d], 1);
    col[pos] = src[e];
  }
}

// ---------------------------------------------------------------- weight prep
// Lane-ordered MFMA B-fragments for the two 128x128 MLP weights.
__global__ __launch_bounds__(256) void wprep_k(const float* __restrict__ fc1_W,
                                               const float* __restrict__ fc2_W,
                                               _Float16* __restrict__ Wb) {
  int idx = blockIdx.x * 256 + threadIdx.x;
  if (idx < 2 * 16384) {
    int mat = idx >> 14;
    int r = idx & 16383;
    int t = r >> 11;
    int ktb = (r >> 9) & 3;
    int lane = (r >> 3) & 63;
    int j = r & 7;
    int m = lane & 15, q = lane >> 4;
    int k = ktb * 32 + q * 8 + j;
    int n = t * 16 + m;
    const float* W = (mat == 0) ? fc1_W : fc2_W;
    Wb[idx] = (_Float16)W[(size_t)k * 128 + n];
  }
}

// ------------------------------------- parallel weight chain (R13)
__global__ __launch_bounds__(256) void chain_mm_k(const float* __restrict__ A,
                                                  const float* __restrict__ B,
                                                  float* __restrict__ C) {
  __shared__ float Bl[2048];
  int t = threadIdx.x;
  for (int i = t; i < 2048; i += 256) Bl[i] = B[i];
  __syncthreads();
  int idx = blockIdx.x * 256 + t;
  int row = idx >> 4, f = idx & 15;
  const float* Ar = A + (size_t)row * 128;
  float s = 0.f;
#pragma unroll 8
  for (int j = 0; j < 128; ++j) s = fmaf(Ar[j], Bl[j * 16 + f], s);
  C[idx] = s;
}

__global__ __launch_bounds__(256) void chain_frag_k(const float* __restrict__ W0,
                                                    const float* __restrict__ T1,
                                                    const float* __restrict__ T2,
                                                    const float* __restrict__ assign_W,
                                                    const float* __restrict__ gcn_b,
                                                    _Float16* __restrict__ WbT,
                                                    float* __restrict__ cvec) {
  int t = threadIdx.x;
  if (blockIdx.x < 8) {
    __shared__ float T1l[2048];
    for (int i = t; i < 2048; i += 256) T1l[i] = T1[i];
    __syncthreads();
    int idx = blockIdx.x * 256 + t;
    int ktb = idx >> 9;
    int lane = (idx >> 3) & 63;
    int jj = idx & 7;
    int m = lane & 15, qq = lane >> 4;
    int k = ktb * 32 + qq * 8 + jj;
    const float* Ar = W0 + (size_t)k * 128;
    float s = 0.f;
#pragma unroll 8
    for (int j = 0; j < 128; ++j) s = fmaf(Ar[j], T1l[j * 16 + m], s);
    WbT[idx] = (_Float16)s;
  } else {
    if (t < 16) {
      float s3 = 0.f, s2 = 0.f, s1 = 0.f;
      for (int k = 0; k < 128; ++k) {
        s3 += gcn_b[k] * T1[k * 16 + t];
        s2 += gcn_b[128 + k] * T2[k * 16 + t];
        s1 += gcn_b[256 + k] * assign_W[k * 16 + t];
      }
      cvec[t] = s3;
      cvec[16 + t] = s2;
      cvec[32 + t] = s1;
    }
  }
}

// ------------------------------------- fused MLP + projection (R14/R16, proven)
// One wave owns 16 rows. B-frags for the current stage live in LDS (staged
// once per block, shared by 4 waves). X row-loads issued before staging.
__global__ __launch_bounds__(256) void mlp_fused_k(const float* __restrict__ X,
                                                   const _Float16* __restrict__ Wb,
                                                   const float* __restrict__ fc1_b,
                                                   const float* __restrict__ fc2_b,
                                                   const _Float16* __restrict__ WbT,
                                                   const float* __restrict__ dinv,
                                                   _Float16* __restrict__ S, int N) {
  __shared__ _Float16 Wst[16384];       // 32KB: current stage's B-frags
  __shared__ _Float16 hl[4][16 * 136];  // per-wave intermediate (pad 136)
  const int tid = threadIdx.x;
  const int w = tid >> 6, lane = tid & 63;
  const int m = lane & 15, q = lane >> 4;
  const int r0 = (blockIdx.x * 4 + w) * 16;
  const int rowA = r0 + m;
  const bool validA = rowA < N;
  _Float16* hw = hl[w];

  // ---- issue X loads first (HBM latency hides under staging + barrier)
  float4 xa[8];
#pragma unroll
  for (int ktb = 0; ktb < 4; ++ktb) {
    if (validA) {
      const float* Ap = X + (size_t)rowA * 128 + ktb * 32 + q * 8;
      xa[2 * ktb] = *(const float4*)Ap;
      xa[2 * ktb + 1] = *(const float4*)(Ap + 4);
    } else {
      xa[2 * ktb] = (float4){0.f, 0.f, 0.f, 0.f};
      xa[2 * ktb + 1] = (float4){0.f, 0.f, 0.f, 0.f};
    }
  }
  // ---- stage fc1 B-frags into LDS (32KB, cooperative)
  {
    half8 v[8];
#pragma unroll
    for (int i = 0; i < 8; ++i) v[i] = *(const half8*)(Wb + ((size_t)(i * 256 + tid)) * 8);
#pragma unroll
    for (int i = 0; i < 8; ++i) *(half8*)(Wst + (size_t)(i * 256 + tid) * 8) = v[i];
  }
  __syncthreads();

  // ---- fc1: A = X (f32 -> f16), B from LDS
  floatx4 acc[8];
#pragma unroll
  for (int t = 0; t < 8; ++t) acc[t] = (floatx4){0.f, 0.f, 0.f, 0.f};
#pragma unroll
  for (int ktb = 0; ktb < 4; ++ktb) {
    half8 a;
    float4 f0 = xa[2 * ktb], f1 = xa[2 * ktb + 1];
    a[0] = (_Float16)f0.x; a[1] = (_Float16)f0.y;
    a[2] = (_Float16)f0.z; a[3] = (_Float16)f0.w;
    a[4] = (_Float16)f1.x; a[5] = (_Float16)f1.y;
    a[6] = (_Float16)f1.z; a[7] = (_Float16)f1.w;
#pragma unroll
    for (int t = 0; t < 8; ++t) {
      half8 b = *(const half8*)(Wst + ((size_t)(t * 4 + ktb) * 64 + lane) * 8);
      acc[t] = __builtin_amdgcn_mfma_f32_16x16x32_f16(a, b, acc[t], 0, 0, 0);
    }
  }
  // ---- sigmoid + transpose to per-wave LDS (row = q*4+r, col = t*16+m)
#pragma unroll
  for (int t = 0; t < 8; ++t) {
    int colg = t * 16 + m;
    float bz = fc1_b[colg];
#pragma unroll
    for (int r = 0; r < 4; ++r) {
      float v = acc[t][r] + bz;
      v = 1.f / (1.f + __expf(-v));
      hw[(q * 4 + r) * 136 + colg] = (_Float16)v;
    }
  }
  __syncthreads();  // all waves done reading fc1 B-frags
  // ---- stage fc2 B-frags (overwrite Wst)
  {
    const _Float16* Wb2 = Wb + 16384;
    half8 v[8];
#pragma unroll
    for (int i = 0; i < 8; ++i) v[i] = *(const half8*)(Wb2 + ((size_t)(i * 256 + tid)) * 8);
#pragma unroll
    for (int i = 0; i < 8; ++i) *(half8*)(Wst + (size_t)(i * 256 + tid) * 8) = v[i];
  }
  __syncthreads();

  // ---- fc2: A from per-wave LDS, B from LDS
#pragma unroll
  for (int t = 0; t < 8; ++t) acc[t] = (floatx4){0.f, 0.f, 0.f, 0.f};
#pragma unroll
  for (int ktb = 0; ktb < 4; ++ktb) {
    half8 a = *(const half8*)(hw + m * 136 + ktb * 32 + q * 8);
#pragma unroll
    for (int t = 0; t < 8; ++t) {
      half8 b = *(const half8*)(Wst + ((size_t)(t * 4 + ktb) * 64 + lane) * 8);
      acc[t] = __builtin_amdgcn_mfma_f32_16x16x32_f16(a, b, acc[t], 0, 0, 0);
    }
  }
#pragma unroll
  for (int t = 0; t < 8; ++t) {
    int colg = t * 16 + m;
    float bz = fc2_b[colg];
#pragma unroll
    for (int r = 0; r < 4; ++r) {
      float v = acc[t][r] + bz;
      v = 1.f / (1.f + __expf(-v));
      hw[(q * 4 + r) * 136 + colg] = (_Float16)v;
    }
  }
  // ---- proj: S = (h2 @ Wt0) * dinv, 16 cols (WbT tiny, L1-hot)
  floatx4 p0 = (floatx4){0.f, 0.f, 0.f, 0.f};
#pragma unroll
  for (int ktb = 0; ktb < 4; ++ktb) {
    half8 a = *(const half8*)(hw + m * 136 + ktb * 32 + q * 8);
    half8 b = *(const half8*)(WbT + ((size_t)ktb * 64 + lane) * 8);
    p0 = __builtin_amdgcn_mfma_f32_16x16x32_f16(a, b, p0, 0, 0, 0);
  }
#pragma unroll
  for (int r = 0; r < 4; ++r) {
    int row = r0 + q * 4 + r;
    if (row < N) S[(size_t)row * 16 + m] = (_Float16)(p0[r] * dinv[row]);
  }
}

// ---------------------------------------------------------------- aggregation
// R20 (proven): pull-mode, 4 ADJACENT nodes per wave over the merged
// contiguous CSR range [rowptr[n0], rowptr[n0+4]). Slot j takes 1/4 of
// merged edges, 8-wide gather unroll. Cumulative-prefix steering; per-node
// sums recovered as differences after the slot-reduce. Slot j finalizes
// node n0+j. S_next[i] = rowscale[i]*(sum S[src] + S[i]) + bm[i]*c[f].
template <bool FOUT32>
__global__ __launch_bounds__(256) void agg16q_k(const _Float16* __restrict__ xw,
                                                const int* __restrict__ rowptr,
                                                const int* __restrict__ col,
                                                const float* __restrict__ rowscale,
                                                const float* __restrict__ biasmul,
                                                const float* __restrict__ c,
                                                void* __restrict__ outv, int N) {
  int w = blockIdx.x * 4 + (threadIdx.x >> 6);
  int n0 = w * 4;
  if (n0 >= N) return;
  int lane = threadIdx.x & 63;
  int f = lane & 15;
  int j = lane >> 4;
  int b0 = rowptr[n0];
  int s1 = rowptr[min(n0 + 1, N)];
  int s2 = rowptr[min(n0 + 2, N)];
  int s3 = rowptr[min(n0 + 3, N)];
  int e4 = rowptr[min(n0 + 4, N)];
  int D = e4 - b0;
  int q = (D + 3) >> 2;
  int e = b0 + j * q;
  int ee = min(e + q, e4);
  float p0 = 0.f, p1 = 0.f, p2 = 0.f, p3 = 0.f;
  for (; e + 7 < ee; e += 8) {
    int cc[8];
#pragma unroll
    for (int i = 0; i < 8; ++i) cc[i] = col[e + i];
    float vv[8];
#pragma unroll
    for (int i = 0; i < 8; ++i) vv[i] = (float)xw[(size_t)cc[i] * 16 + f];
#pragma unroll
    for (int i = 0; i < 8; ++i) {
      int ei = e + i;
      float v = vv[i];
      p0 += (ei < s1) ? v : 0.f;
      p1 += (ei < s2) ? v : 0.f;
      p2 += (ei < s3) ? v : 0.f;
      p3 += v;
    }
  }
  for (; e < ee; ++e) {
    float v = (float)xw[(size_t)col[e] * 16 + f];
    p0 += (e < s1) ? v : 0.f;
    p1 += (e < s2) ? v : 0.f;
    p2 += (e < s3) ? v : 0.f;
    p3 += v;
  }
  p0 += __shfl_xor(p0, 16, 64);
  p0 += __shfl_xor(p0, 32, 64);
  p1 += __shfl_xor(p1, 16, 64);
  p1 += __shfl_xor(p1, 32, 64);
  p2 += __shfl_xor(p2, 16, 64);
  p2 += __shfl_xor(p2, 32, 64);
  p3 += __shfl_xor(p3, 16, 64);
  p3 += __shfl_xor(p3, 32, 64);
  float mine = (j == 0) ? p0 : (j == 1) ? (p1 - p0) : (j == 2) ? (p2 - p1) : (p3 - p2);
  int nj = n0 + j;
  if (nj < N) {
    float a = mine + (float)xw[(size_t)nj * 16 + f];
    float bm = biasmul ? biasmul[nj] : 1.f;
    float o = fmaf(a, rowscale[nj], bm * c[f]);
    if (FOUT32)
      ((float*)outv)[(size_t)nj * 16 + f] = o;
    else
      ((_Float16*)outv)[(size_t)nj * 16 + f] = (_Float16)o;
  }
}

// ---------------------------------------------------------------- launch
extern "C" void kernel_launch(void* const* d_in, const int* in_sizes, int n_in,
                              void* d_out, int out_size, void* d_ws, size_t ws_size,
                              hipStream_t stream) {
  const int* adj = (const int*)d_in[0];
  const float* X = (const float*)d_in[1];
  const float* fc1_W = (const float*)d_in[2];
  const float* fc1_b = (const float*)d_in[3];
  const float* fc2_W = (const float*)d_in[4];
  const float* fc2_b = (const float*)d_in[5];
  const float* gcn_W = (const float*)d_in[6];
  const float* gcn_b = (const float*)d_in[7];
  const float* assign_W = (const float*)d_in[8];
  const float* assign_b = (const float*)d_in[9];
  const int E = in_sizes[0] / 2;
  const int N = in_sizes[1] / 128;
  const int* src = adj;
  const int* dst = adj + E;

  char* ws = (char*)d_ws;
  size_t off = 0;
  auto alloc = [&](size_t bytes) {
    void* p = ws + off;
    off = (off + bytes + 511) & ~(size_t)511;
    return p;
  };
  const int G = 1024;  // R23: 4 blocks/CU for p1a/p1c (was 256 = 1/CU)
  const int B = (N + 511) >> 9;
  const int L = B * G;
  _Float16* SA = (_Float16*)alloc((size_t)N * 16 * 2);  // 3.2 MB state
  _Float16* SB = (_Float16*)alloc((size_t)N * 16 * 2);  // 3.2 MB state
  _Float16* Wb = (_Float16*)alloc((size_t)2 * 16384 * 2);
  _Float16* WbT = (_Float16*)alloc(2048 * 2);
  float* T2g = (float*)alloc(2048 * 4);
  float* T1g = (float*)alloc(2048 * 4);
  float* cvec = (float*)alloc(48 * 4);
  float* dinv = (float*)alloc((size_t)N * 4);
  float* dinv2 = (float*)alloc((size_t)N * 4);
  int* rowptr = (int*)alloc((size_t)(N + 1) * 4);
  int* col = (int*)alloc((size_t)E * 4);
  uint32_t* tmp = (uint32_t*)alloc((size_t)E * 4);
  int* M = (int*)alloc((size_t)L * 4);
  int* scanned = (int*)alloc((size_t)(L + 1) * 4);
  int* scanscratch = (int*)alloc((size_t)L * 4);
  int* bsum = (int*)alloc(4096);
  int* cnt = (int*)alloc((size_t)N * 4);     // fallback path only
  int* cursor = (int*)alloc((size_t)N * 4);  // fallback path only

  wprep_k<<<(2 * 16384 + 255) / 256, 256, 0, stream>>>(fc1_W, fc2_W, Wb);
  // parallel weight chain: T2 = W2@Wa, T1 = W1@T2, WbT = frag(W0@T1), cvec
  chain_mm_k<<<8, 256, 0, stream>>>(gcn_W + 32768, assign_W, T2g);
  chain_mm_k<<<8, 256, 0, stream>>>(gcn_W + 16384, T2g, T1g);
  chain_frag_k<<<9, 256, 0, stream>>>(gcn_W, T1g, T2g, assign_W, gcn_b, WbT, cvec);

  if (N <= (1 << 17)) {
    const int chunk = (E + G - 1) / G;
    const int NBL = (L + SCAN_CHUNK - 1) / SCAN_CHUNK;
    p1a_hist_k<<<G, 256, 0, stream>>>(dst, E, G, B, chunk, M);
    scan_partial_k<<<NBL, 256, 0, stream>>>(M, L, bsum);
    scan_bsum_k<<<1, 64, 0, stream>>>(bsum, NBL);
    scan_apply_k<<<NBL, 256, 0, stream>>>(M, bsum, L, scanned, scanscratch, E);
    p1c_scatter_k<<<G, 256, 0, stream>>>(src, dst, E, G, B, chunk, scanned, tmp);
    p2_build_k<<<B, 256, 0, stream>>>(tmp, scanned, G, N, E, rowptr, col, dinv, dinv2);
  } else {
    const int NB = (N + SCAN_CHUNK - 1) / SCAN_CHUNK;
    hipMemsetAsync(cnt, 0, (size_t)N * 4, stream);
    count_edges_k<<<2048, 256, 0, stream>>>(dst, E, cnt);
    dinv_k<<<(N + 255) / 256, 256, 0, stream>>>(cnt, dinv, dinv2, N);
    scan_partial_k<<<NB, 256, 0, stream>>>(cnt, N, bsum);
    scan_bsum_k<<<1, 64, 0, stream>>>(bsum, NB);
    scan_apply_k<<<NB, 256, 0, stream>>>(cnt, bsum, N, rowptr, cursor, E);
    fill_k<<<2048, 256, 0, stream>>>(src, dst, E, cursor, col);
  }

  int gfuse = (N + 63) / 64;
  int ab = (N + 15) / 16;  // 4 nodes/wave, 4 waves/block
  // Fused MLP front-end + collapsed-weight projection (needs dinv from CSR).
  mlp_fused_k<<<gfuse, 256, 0, stream>>>(X, Wb, fc1_b, fc2_b, WbT, dinv, SA, N);
  // Collapsed linear graph stack: S = D^{-1/2} z, z <- Az + 1 c^T, 4 times.
  agg16q_k<false><<<ab, 256, 0, stream>>>(SA, rowptr, col, dinv2, dinv, cvec, SB, N);
  agg16q_k<false><<<ab, 256, 0, stream>>>(SB, rowptr, col, dinv2, dinv, cvec + 16, SA, N);
  agg16q_k<false><<<ab, 256, 0, stream>>>(SA, rowptr, col, dinv2, dinv, cvec + 32, SB, N);
  agg16q_k<true><<<ab, 256, 0, stream>>>(SB, rowptr, col, dinv, nullptr, assign_b,
                                         (float*)d_out, N);
}